// Round 3
// baseline (334.171 us; speedup 1.0000x reference)
//
#include <hip/hip_runtime.h>

typedef __attribute__((ext_vector_type(8))) short bf16x8_t;
typedef __attribute__((ext_vector_type(4))) float f32x4_t;

#define N_HEAD 12
#define SEQ_T 1024
#define CDIM 768
#define HDIM 64

__device__ __forceinline__ float bf2f(unsigned short u) {
    union { unsigned int u; float f; } v;
    v.u = ((unsigned int)u) << 16;
    return v.f;
}
__device__ __forceinline__ unsigned short f2bf(float f) {
    union { float f; unsigned int u; } v;
    v.f = f;
    unsigned int r = (v.u + 0x7fffu + ((v.u >> 16) & 1u)) >> 16;
    return (unsigned short)r;
}

// ---- dtype detection: flag=0 -> inputs are bf16, flag=1 -> inputs are fp32 ----
// Sample even-indexed ushorts of x. bf16 buffer: these are bf16 values of N(0,1)
// (exponent in [96,143], ~never zero). fp32 buffer: these are low mantissa halves
// (random -> ~19% "sane"; or all-zero if values were bf16-rounded fp32).
__global__ __launch_bounds__(256) void detect_dtype(
    const unsigned short* __restrict__ x, int* __restrict__ flag)
{
    __shared__ int s_sane, s_zero;
    if (threadIdx.x == 0) { s_sane = 0; s_zero = 0; }
    __syncthreads();
    int sane = 0, zero = 0;
    for (int k = 0; k < 8; k++) {
        unsigned short u = x[(threadIdx.x * 8 + k) * 2];   // even indices 0..4094
        if (u == 0) zero++;
        else {
            int e = (u >> 7) & 0xFF;
            if (e >= 96 && e <= 143) sane++;
        }
    }
    atomicAdd(&s_sane, sane);
    atomicAdd(&s_zero, zero);
    __syncthreads();
    if (threadIdx.x == 0) {
        // zeros dominate -> bf16-rounded fp32; mostly sane -> bf16; else fp32
        int f;
        if (s_zero >= 1024)      f = 1;
        else if (s_sane >= 1024) f = 0;
        else                     f = 1;
        *flag = f;
    }
}

// dst[i] = bf16(src[i]) with src dtype per flag
__global__ __launch_bounds__(256) void cvt_copy(
    const void* __restrict__ src, unsigned short* __restrict__ dst,
    const int* __restrict__ flag, int n)
{
    int i = blockIdx.x * 256 + threadIdx.x;
    if (i < n) {
        if (*flag) dst[i] = f2bf(((const float*)src)[i]);
        else       dst[i] = ((const unsigned short*)src)[i];
    }
}

// dst[c*R + r] = bf16(src[r*Cc + c]) with src dtype per flag
__global__ __launch_bounds__(256) void cvt_transpose(
    const void* __restrict__ src, unsigned short* __restrict__ dst,
    const int* __restrict__ flag, int R, int Cc)
{
    int idx = blockIdx.x * 256 + threadIdx.x;
    if (idx < R * Cc) {
        int c = idx / R;
        int r = idx - c * R;
        size_t s = (size_t)r * Cc + c;
        if (*flag) dst[idx] = f2bf(((const float*)src)[s]);
        else       dst[idx] = ((const unsigned short*)src)[s];
    }
}

// 128x128 tile GEMM core: C[m][n] = sum_k A[m][k] * Bt[n][k], K=768, bf16 in, fp32 acc.
__device__ __forceinline__ void gemm128_core(
    const unsigned short* __restrict__ A, const unsigned short* __restrict__ Bt,
    unsigned short* As, unsigned short* Bs, f32x4_t acc[4][4], int mBase, int nBase)
{
    const int tid  = threadIdx.x;
    const int lane = tid & 63;
    const int wv   = tid >> 6;
    const int quad = lane >> 4;
    const int l16  = lane & 15;
    const int wm   = (wv >> 1) * 64;
    const int wn   = (wv & 1) * 64;

    f32x4_t zero = {0.f, 0.f, 0.f, 0.f};
#pragma unroll
    for (int tm = 0; tm < 4; tm++)
#pragma unroll
        for (int tn = 0; tn < 4; tn++)
            acc[tm][tn] = zero;

    for (int kt = 0; kt < 768; kt += 64) {
#pragma unroll
        for (int i = 0; i < 4; i++) {
            int ci = i * 256 + tid;              // 16B chunk index 0..1023
            int r = ci >> 3;
            int koff = (ci & 7) << 3;
            *(int4*)(As + ci * 8) = *(const int4*)(A  + (size_t)(mBase + r) * 768 + kt + koff);
            *(int4*)(Bs + ci * 8) = *(const int4*)(Bt + (size_t)(nBase + r) * 768 + kt + koff);
        }
        __syncthreads();
#pragma unroll
        for (int ks = 0; ks < 2; ks++) {
            bf16x8_t af[4], bfv[4];
#pragma unroll
            for (int tm = 0; tm < 4; tm++)
                af[tm] = *(const bf16x8_t*)(As + (wm + tm * 16 + l16) * 64 + ks * 32 + quad * 8);
#pragma unroll
            for (int tn = 0; tn < 4; tn++)
                bfv[tn] = *(const bf16x8_t*)(Bs + (wn + tn * 16 + l16) * 64 + ks * 32 + quad * 8);
#pragma unroll
            for (int tm = 0; tm < 4; tm++)
#pragma unroll
                for (int tn = 0; tn < 4; tn++)
                    acc[tm][tn] = __builtin_amdgcn_mfma_f32_16x16x32_bf16(
                        af[tm], bfv[tn], acc[tm][tn], 0, 0, 0);
        }
        __syncthreads();
    }
}

// GEMM1: qkv = x @ w_attn + b_attn, scattered to q[B,H,T,D], k[B,H,T,D], v[B,H,D,T]
__global__ __launch_bounds__(256) void gemm_qkv(
    const unsigned short* __restrict__ x, const unsigned short* __restrict__ waT,
    const unsigned short* __restrict__ b_attn,
    unsigned short* __restrict__ qb, unsigned short* __restrict__ kb, unsigned short* __restrict__ vb)
{
    __shared__ __align__(16) unsigned short As[128 * 64];
    __shared__ __align__(16) unsigned short Bs[128 * 64];
    f32x4_t acc[4][4];
    const int mBase = blockIdx.y * 128;
    const int nBase = blockIdx.x * 128;
    gemm128_core(x, waT, As, Bs, acc, mBase, nBase);

    const int tid = threadIdx.x;
    const int lane = tid & 63, wv = tid >> 6;
    const int quad = lane >> 4, l16 = lane & 15;
    const int wm = (wv >> 1) * 64, wn = (wv & 1) * 64;

#pragma unroll
    for (int tn = 0; tn < 4; tn++) {
        int n = nBase + wn + tn * 16 + l16;                 // 0..2303
        float bv = bf2f(b_attn[n]);
        int part = (n >= 1536) ? 2 : ((n >= 768) ? 1 : 0);  // q/k/v
        int f = n - part * 768;
        int h = f >> 6, d = f & 63;
#pragma unroll
        for (int tm = 0; tm < 4; tm++) {
#pragma unroll
            for (int i = 0; i < 4; i++) {
                int row = mBase + wm + tm * 16 + quad * 4 + i;   // 0..8191 = b*1024+t
                int b = row >> 10, t = row & 1023;
                unsigned short hv = f2bf(acc[tm][tn][i] + bv);
                size_t bh = (size_t)(b * N_HEAD + h);
                if (part == 0)      qb[(bh * SEQ_T + t) * HDIM + d] = hv;
                else if (part == 1) kb[(bh * SEQ_T + t) * HDIM + d] = hv;
                else                vb[(bh * HDIM + d) * SEQ_T + t] = hv;
            }
        }
    }
}

// Fused causal attention: one block per (64-row q tile, head, batch). 4 waves,
// wave w owns rows [w*16, w*16+16). Online softmax, P via LDS round-trip, O = P V.
__global__ __launch_bounds__(256) void attn_fused(
    const unsigned short* __restrict__ qb, const unsigned short* __restrict__ kb,
    const unsigned short* __restrict__ vb, unsigned short* __restrict__ attb)
{
    __shared__ __align__(16) unsigned short Ksh[64 * 64];
    __shared__ __align__(16) unsigned short Vsh[64 * 64];   // V^T tile: [d][s]
    __shared__ __align__(16) unsigned short Psh[4 * 16 * 64];

    const int qi = blockIdx.x;      // 0..15 (q tile)
    const int h  = blockIdx.y;      // 0..11
    const int b  = blockIdx.z;      // 0..7
    const int tid = threadIdx.x;
    const int lane = tid & 63, wv = tid >> 6;
    const int quad = lane >> 4, l16 = lane & 15;

    const size_t bh = (size_t)(b * N_HEAD + h);
    const int qbase = qi * 64;

    bf16x8_t qf[2];
    const unsigned short* qrow = qb + (bh * SEQ_T + qbase + wv * 16 + l16) * HDIM;
#pragma unroll
    for (int kc = 0; kc < 2; kc++)
        qf[kc] = *(const bf16x8_t*)(qrow + kc * 32 + quad * 8);

    f32x4_t zero = {0.f, 0.f, 0.f, 0.f};
    f32x4_t o_acc[4];
#pragma unroll
    for (int c = 0; c < 4; c++) o_acc[c] = zero;
    float m_st[4], l_st[4];
#pragma unroll
    for (int i = 0; i < 4; i++) { m_st[i] = -1e30f; l_st[i] = 0.f; }

    for (int kt = 0; kt <= qi; kt++) {
        __syncthreads();
#pragma unroll
        for (int i = 0; i < 2; i++) {
            int ci = i * 256 + tid;          // 0..511 16B chunks
            int r = ci >> 3;
            int off = (ci & 7) << 3;
            *(int4*)(Ksh + ci * 8) = *(const int4*)(kb + (bh * SEQ_T + kt * 64 + r) * HDIM + off);
            *(int4*)(Vsh + ci * 8) = *(const int4*)(vb + (bh * HDIM + r) * SEQ_T + kt * 64 + off);
        }
        __syncthreads();

        // S = Q K^T  (no 1/sqrt(D) scale — faithful to reference)
        f32x4_t s_acc[4];
#pragma unroll
        for (int c = 0; c < 4; c++) {
            s_acc[c] = zero;
#pragma unroll
            for (int kc = 0; kc < 2; kc++) {
                bf16x8_t kf = *(const bf16x8_t*)(Ksh + (c * 16 + l16) * 64 + kc * 32 + quad * 8);
                s_acc[c] = __builtin_amdgcn_mfma_f32_16x16x32_bf16(qf[kc], kf, s_acc[c], 0, 0, 0);
            }
        }

        if (kt == qi) {   // diagonal tile: causal mask col>row
#pragma unroll
            for (int c = 0; c < 4; c++)
#pragma unroll
                for (int i = 0; i < 4; i++) {
                    int col = c * 16 + l16;
                    int row = wv * 16 + quad * 4 + i;
                    if (col > row) s_acc[c][i] = -1e30f;
                }
        }

        float mloc[4];
#pragma unroll
        for (int i = 0; i < 4; i++)
            mloc[i] = fmaxf(fmaxf(s_acc[0][i], s_acc[1][i]), fmaxf(s_acc[2][i], s_acc[3][i]));
#pragma unroll
        for (int off = 1; off < 16; off <<= 1)
#pragma unroll
            for (int i = 0; i < 4; i++)
                mloc[i] = fmaxf(mloc[i], __shfl_xor(mloc[i], off));

        float alpha[4];
#pragma unroll
        for (int i = 0; i < 4; i++) {
            float mn = fmaxf(m_st[i], mloc[i]);
            alpha[i] = __expf(m_st[i] - mn);
            m_st[i] = mn;
        }
#pragma unroll
        for (int c = 0; c < 4; c++)
#pragma unroll
            for (int i = 0; i < 4; i++)
                s_acc[c][i] = __expf(s_acc[c][i] - m_st[i]);

        float psum[4];
#pragma unroll
        for (int i = 0; i < 4; i++)
            psum[i] = s_acc[0][i] + s_acc[1][i] + s_acc[2][i] + s_acc[3][i];
#pragma unroll
        for (int off = 1; off < 16; off <<= 1)
#pragma unroll
            for (int i = 0; i < 4; i++)
                psum[i] += __shfl_xor(psum[i], off);
#pragma unroll
        for (int i = 0; i < 4; i++)
            l_st[i] = alpha[i] * l_st[i] + psum[i];
#pragma unroll
        for (int c = 0; c < 4; c++)
#pragma unroll
            for (int i = 0; i < 4; i++)
                o_acc[c][i] *= alpha[i];

        // P: C-layout -> LDS -> A-layout (cross-lane: barrier required)
        unsigned short* pw = Psh + wv * 16 * 64;
#pragma unroll
        for (int c = 0; c < 4; c++)
#pragma unroll
            for (int i = 0; i < 4; i++)
                pw[(quad * 4 + i) * 64 + c * 16 + l16] = f2bf(s_acc[c][i]);

        __syncthreads();

        bf16x8_t pf[2];
#pragma unroll
        for (int kc = 0; kc < 2; kc++)
            pf[kc] = *(const bf16x8_t*)(pw + l16 * 64 + kc * 32 + quad * 8);
#pragma unroll
        for (int c = 0; c < 4; c++)
#pragma unroll
            for (int kc = 0; kc < 2; kc++) {
                bf16x8_t vf = *(const bf16x8_t*)(Vsh + (c * 16 + l16) * 64 + kc * 32 + quad * 8);
                o_acc[c] = __builtin_amdgcn_mfma_f32_16x16x32_bf16(pf[kc], vf, o_acc[c], 0, 0, 0);
            }
    }

    float inv_l[4];
#pragma unroll
    for (int i = 0; i < 4; i++) inv_l[i] = 1.f / l_st[i];
#pragma unroll
    for (int c = 0; c < 4; c++)
#pragma unroll
        for (int i = 0; i < 4; i++) {
            int row = qbase + wv * 16 + quad * 4 + i;
            attb[((size_t)b * SEQ_T + row) * CDIM + h * HDIM + c * 16 + l16] =
                f2bf(o_acc[c][i] * inv_l[i]);
        }
}

// GEMM2: out = att @ w_proj + b_proj, output dtype per flag
__global__ __launch_bounds__(256) void gemm_proj(
    const unsigned short* __restrict__ attb, const unsigned short* __restrict__ wpT,
    const unsigned short* __restrict__ b_proj, void* __restrict__ outv,
    const int* __restrict__ flag)
{
    __shared__ __align__(16) unsigned short As[128 * 64];
    __shared__ __align__(16) unsigned short Bs[128 * 64];
    f32x4_t acc[4][4];
    const int mBase = blockIdx.y * 128;
    const int nBase = blockIdx.x * 128;
    gemm128_core(attb, wpT, As, Bs, acc, mBase, nBase);

    const int tid = threadIdx.x;
    const int lane = tid & 63, wv = tid >> 6;
    const int quad = lane >> 4, l16 = lane & 15;
    const int wm = (wv >> 1) * 64, wn = (wv & 1) * 64;
    const int f32out = *flag;

#pragma unroll
    for (int tn = 0; tn < 4; tn++) {
        int n = nBase + wn + tn * 16 + l16;     // 0..767
        float bv = bf2f(b_proj[n]);
#pragma unroll
        for (int tm = 0; tm < 4; tm++) {
#pragma unroll
            for (int i = 0; i < 4; i++) {
                int row = mBase + wm + tm * 16 + quad * 4 + i;
                float val = acc[tm][tn][i] + bv;
                size_t idx = (size_t)row * CDIM + n;
                if (f32out) ((float*)outv)[idx] = val;
                else        ((unsigned short*)outv)[idx] = f2bf(val);
            }
        }
    }
}

extern "C" void kernel_launch(void* const* d_in, const int* in_sizes, int n_in,
                              void* d_out, int out_size, void* d_ws, size_t ws_size,
                              hipStream_t stream) {
    const void* x      = d_in[0];  // [8,1024,768]
    const void* w_attn = d_in[1];  // [768,2304]
    const void* b_attn = d_in[2];  // [2304]
    const void* w_proj = d_in[3];  // [768,768]
    const void* b_proj = d_in[4];  // [768]

    unsigned short* ws    = (unsigned short*)d_ws;
    unsigned short* waT   = ws;                   // 1,769,472
    unsigned short* wpT   = waT + 1769472;        //   589,824
    unsigned short* xbf   = wpT + 589824;         // 6,291,456
    unsigned short* ba_bf = xbf + 6291456;        //     2,304
    unsigned short* bp_bf = ba_bf + 2304;         //       768
    int*            flag  = (int*)(ws + 8653824); // 4B flag (aligned)
    unsigned short* qb    = ws + 8653832;         // 6,291,456  [B,H,T,D]
    unsigned short* kb    = qb + 6291456;         // 6,291,456  [B,H,T,D]
    unsigned short* vb    = kb + 6291456;         // 6,291,456  [B,H,D,T]
    unsigned short* attb  = vb + 6291456;         // 6,291,456  [B,T,C]
    // total ws use: 67,639,312 bytes

    detect_dtype<<<dim3(1), 256, 0, stream>>>((const unsigned short*)x, flag);
    cvt_copy<<<dim3(24576), 256, 0, stream>>>(x, xbf, flag, 6291456);
    cvt_copy<<<dim3(9), 256, 0, stream>>>(b_attn, ba_bf, flag, 2304);
    cvt_copy<<<dim3(3), 256, 0, stream>>>(b_proj, bp_bf, flag, 768);
    cvt_transpose<<<dim3(6912), 256, 0, stream>>>(w_attn, waT, flag, 768, 2304);
    cvt_transpose<<<dim3(2304), 256, 0, stream>>>(w_proj, wpT, flag, 768, 768);
    gemm_qkv<<<dim3(18, 64), 256, 0, stream>>>(xbf, waT, ba_bf, qb, kb, vb);
    attn_fused<<<dim3(16, N_HEAD, 8), 256, 0, stream>>>(qb, kb, vb, attb);
    gemm_proj<<<dim3(6, 64), 256, 0, stream>>>(attb, wpT, bp_bf, d_out, flag);
}

// Round 4
// 212.055 us; speedup vs baseline: 1.5759x; 1.5759x over previous
//
#include <hip/hip_runtime.h>

typedef __attribute__((ext_vector_type(8))) short bf16x8_t;
typedef __attribute__((ext_vector_type(4))) float f32x4_t;

#define AS1C(p) ((const __attribute__((address_space(1))) void*)(p))
#define AS3(p)  ((__attribute__((address_space(3))) void*)(p))

#define N_HEAD 12
#define SEQ_T 1024
#define CDIM 768
#define HDIM 64
#define L2E 1.44269504f

__device__ __forceinline__ unsigned short f2bf(float f) {
    union { float f; unsigned int u; } v;
    v.f = f;
    unsigned int r = (v.u + 0x7fffu + ((v.u >> 16) & 1u)) >> 16;
    return (unsigned short)r;
}

// x fp32 -> bf16, vectorized
__global__ __launch_bounds__(256) void cvt_x(
    const float4* __restrict__ src, ushort4* __restrict__ dst, int n4)
{
    int i = blockIdx.x * 256 + threadIdx.x;
    if (i < n4) {
        float4 v = src[i];
        ushort4 o;
        o.x = f2bf(v.x); o.y = f2bf(v.y); o.z = f2bf(v.z); o.w = f2bf(v.w);
        dst[i] = o;
    }
}

// dst[c*R + r] = bf16(src[r*Cc + c]); LDS-tiled. grid (Cc/32, R/32), block (32,8)
__global__ __launch_bounds__(256) void cvt_transpose(
    const float* __restrict__ src, unsigned short* __restrict__ dst, int R, int Cc)
{
    __shared__ float tile[32][33];
    int c0 = blockIdx.x * 32, r0 = blockIdx.y * 32;
#pragma unroll
    for (int i = 0; i < 4; i++)
        tile[threadIdx.y + i * 8][threadIdx.x] =
            src[(size_t)(r0 + threadIdx.y + i * 8) * Cc + c0 + threadIdx.x];
    __syncthreads();
#pragma unroll
    for (int i = 0; i < 4; i++)
        dst[(size_t)(c0 + threadIdx.y + i * 8) * R + r0 + threadIdx.x] =
            f2bf(tile[threadIdx.x][threadIdx.y + i * 8]);
}

// 128x128 tile GEMM core, K=768: async global_load_lds width-16 staging (m97 structure)
__device__ __forceinline__ void gemm128_core(
    const unsigned short* __restrict__ A, const unsigned short* __restrict__ Bt,
    unsigned short* As, unsigned short* Bs, f32x4_t acc[4][4], int mBase, int nBase)
{
    const int tid  = threadIdx.x;
    const int lane = tid & 63;
    const int wv   = tid >> 6;
    const int quad = lane >> 4;
    const int l16  = lane & 15;
    const int wm   = (wv >> 1) * 64;
    const int wn   = (wv & 1) * 64;

    f32x4_t zero = {0.f, 0.f, 0.f, 0.f};
#pragma unroll
    for (int tm = 0; tm < 4; tm++)
#pragma unroll
        for (int tn = 0; tn < 4; tn++)
            acc[tm][tn] = zero;

    for (int kt = 0; kt < 768; kt += 64) {
#pragma unroll
        for (int i = 0; i < 4; i++) {
            int cbase = i * 256 + wv * 64;       // wave-uniform chunk base
            int ci = cbase + lane;               // 16B chunk 0..1023
            int r = ci >> 3;
            int koff = (ci & 7) << 3;
            __builtin_amdgcn_global_load_lds(
                AS1C(A + (size_t)(mBase + r) * 768 + kt + koff),
                AS3(As + cbase * 8), 16, 0, 0);
            __builtin_amdgcn_global_load_lds(
                AS1C(Bt + (size_t)(nBase + r) * 768 + kt + koff),
                AS3(Bs + cbase * 8), 16, 0, 0);
        }
        __syncthreads();
#pragma unroll
        for (int ks = 0; ks < 2; ks++) {
            bf16x8_t af[4], bfv[4];
#pragma unroll
            for (int tm = 0; tm < 4; tm++)
                af[tm] = *(const bf16x8_t*)(As + (wm + tm * 16 + l16) * 64 + ks * 32 + quad * 8);
#pragma unroll
            for (int tn = 0; tn < 4; tn++)
                bfv[tn] = *(const bf16x8_t*)(Bs + (wn + tn * 16 + l16) * 64 + ks * 32 + quad * 8);
#pragma unroll
            for (int tm = 0; tm < 4; tm++)
#pragma unroll
                for (int tn = 0; tn < 4; tn++)
                    acc[tm][tn] = __builtin_amdgcn_mfma_f32_16x16x32_bf16(
                        af[tm], bfv[tn], acc[tm][tn], 0, 0, 0);
        }
        __syncthreads();
    }
}

// GEMM1: qkv = x @ w_attn + b_attn; q scaled by log2e; q,k -> [B,H,T,D], v -> [B,H,D,T]
__global__ __launch_bounds__(256) void gemm_qkv(
    const unsigned short* __restrict__ x, const unsigned short* __restrict__ waT,
    const float* __restrict__ b_attn,
    unsigned short* __restrict__ qbuf, unsigned short* __restrict__ kbuf,
    unsigned short* __restrict__ vbuf)
{
    __shared__ __align__(16) unsigned short As[128 * 64];
    __shared__ __align__(16) unsigned short Bs[128 * 64];
    f32x4_t acc[4][4];
    const int mBase = blockIdx.y * 128;
    const int nBase = blockIdx.x * 128;
    gemm128_core(x, waT, As, Bs, acc, mBase, nBase);

    const int tid = threadIdx.x;
    const int lane = tid & 63, wv = tid >> 6;
    const int quad = lane >> 4, l16 = lane & 15;
    const int wm = (wv >> 1) * 64, wn = (wv & 1) * 64;
    const int part = blockIdx.x / 6;    // 0=q 1=k 2=v (block-uniform)

#pragma unroll
    for (int tn = 0; tn < 4; tn++) {
        int n = nBase + wn + tn * 16 + l16;     // 0..2303
        float bv = b_attn[n];
        int f = n - part * 768;
        int hh = f >> 6, d = f & 63;
        if (part == 2) {
#pragma unroll
            for (int tm = 0; tm < 4; tm++) {
                int t0 = mBase + wm + tm * 16 + quad * 4;   // 4-aligned, no b-crossing
                int bb = t0 >> 10, tt = t0 & 1023;
                ushort4 pk;
                pk.x = f2bf(acc[tm][tn][0] + bv);
                pk.y = f2bf(acc[tm][tn][1] + bv);
                pk.z = f2bf(acc[tm][tn][2] + bv);
                pk.w = f2bf(acc[tm][tn][3] + bv);
                *(ushort4*)(vbuf + ((size_t)(bb * N_HEAD + hh) * HDIM + d) * SEQ_T + tt) = pk;
            }
        } else {
            const float scale = (part == 0) ? L2E : 1.f;
            unsigned short* dst = (part == 0) ? qbuf : kbuf;
#pragma unroll
            for (int tm = 0; tm < 4; tm++) {
#pragma unroll
                for (int i = 0; i < 4; i++) {
                    int row = mBase + wm + tm * 16 + quad * 4 + i;
                    int bb = row >> 10, tt = row & 1023;
                    dst[((size_t)(bb * N_HEAD + hh) * SEQ_T + tt) * HDIM + d] =
                        f2bf((acc[tm][tn][i] + bv) * scale);
                }
            }
        }
    }
}

// one 16x64 S/P/O step for one q-tile (Q pre-scaled by log2e; max-free softmax)
__device__ __forceinline__ void attn_tile(
    const bf16x8_t qf[2], const bf16x8_t kf[4][2], const bf16x8_t vf[4][2],
    f32x4_t o[4], float lsum[4], unsigned short* pw,
    int diag, int wv, int quad, int l16)
{
    f32x4_t zero = {0.f, 0.f, 0.f, 0.f};
    f32x4_t s[4];
#pragma unroll
    for (int c = 0; c < 4; c++) {
        s[c] = zero;
#pragma unroll
        for (int kc = 0; kc < 2; kc++)
            s[c] = __builtin_amdgcn_mfma_f32_16x16x32_bf16(qf[kc], kf[c][kc], s[c], 0, 0, 0);
    }
    if (diag) {
#pragma unroll
        for (int c = 0; c < 4; c++)
#pragma unroll
            for (int i = 0; i < 4; i++)
                if (c * 16 + l16 > wv * 16 + quad * 4 + i) s[c][i] = -1e30f;
    }
    float p[4][4];
#pragma unroll
    for (int c = 0; c < 4; c++)
#pragma unroll
        for (int i = 0; i < 4; i++)
            p[c][i] = exp2f(s[c][i]);
#pragma unroll
    for (int i = 0; i < 4; i++)
        lsum[i] += (p[0][i] + p[1][i]) + (p[2][i] + p[3][i]);

    // P: C-layout -> (swizzled, per-wave) LDS -> A-layout. In-wave DS ordering;
    // asm fences stop compiler reordering.
    __asm__ __volatile__("" ::: "memory");
#pragma unroll
    for (int c = 0; c < 4; c++)
#pragma unroll
        for (int i = 0; i < 4; i++) {
            int m = quad * 4 + i;
            pw[m * 64 + (((2 * c + (l16 >> 3)) ^ (m & 7)) << 3) + (l16 & 7)] = f2bf(p[c][i]);
        }
    __asm__ __volatile__("" ::: "memory");
#pragma unroll
    for (int kc = 0; kc < 2; kc++) {
        bf16x8_t pf = *(const bf16x8_t*)(pw + l16 * 64 + (((kc * 4 + quad) ^ (l16 & 7)) << 3));
#pragma unroll
        for (int c = 0; c < 4; c++)
            o[c] = __builtin_amdgcn_mfma_f32_16x16x32_bf16(pf, vf[c][kc], o[c], 0, 0, 0);
    }
}

// Fused causal attention. Block = paired q-tiles (t, 15-t): uniform 17 tile-iters.
// grid (8, 12, 8) = 768 blocks. Double-buffered async K/V staging, swizzled LDS.
__global__ __launch_bounds__(256, 3) void attn_fused(
    const unsigned short* __restrict__ qb, const unsigned short* __restrict__ kb,
    const unsigned short* __restrict__ vb, unsigned short* __restrict__ attb)
{
    __shared__ __align__(16) unsigned short Kbuf[2][64 * 64];
    __shared__ __align__(16) unsigned short Vbuf[2][64 * 64];   // V^T tiles [d][s]
    __shared__ __align__(16) unsigned short Psh[4][16 * 64];

    const int t = blockIdx.x;       // 0..7; tiles t and 15-t
    const int h = blockIdx.y;
    const int b = blockIdx.z;
    const int tid = threadIdx.x;
    const int lane = tid & 63, wv = tid >> 6;
    const int quad = lane >> 4, l16 = lane & 15;
    const int tB = 15 - t, kmax = 15 - t;

    const size_t bh = (size_t)(b * N_HEAD + h);
    const unsigned short* kbase = kb + bh * SEQ_T * HDIM;
    const unsigned short* vbase = vb + bh * HDIM * SEQ_T;
    const unsigned short* qpt   = qb + bh * SEQ_T * HDIM;

    // staging: 512 16B chunks per buffer; wave wv covers chunks [wv*128, wv*128+128)
    // LDS side lane-contiguous; global side granule-permuted (g = gswz ^ (r&7))
    const int j0 = wv * 128 + lane, j1 = j0 + 64;
    const int r0 = j0 >> 3, g0 = (j0 & 7) ^ (r0 & 7);
    const int r1 = j1 >> 3, g1 = (j1 & 7) ^ (r1 & 7);
    const int rgK0 = r0 * 64 + g0 * 8,   rgK1 = r1 * 64 + g1 * 8;
    const int rgV0 = r0 * 1024 + g0 * 8, rgV1 = r1 * 1024 + g1 * 8;
    const int ldsc0 = (wv * 128) * 8, ldsc1 = (wv * 128 + 64) * 8;  // wave-uniform

    bf16x8_t qfA[2], qfB[2];
    {
        const unsigned short* qa = qpt + (size_t)(t * 64 + wv * 16 + l16) * HDIM;
        const unsigned short* qbp = qpt + (size_t)(tB * 64 + wv * 16 + l16) * HDIM;
#pragma unroll
        for (int kc = 0; kc < 2; kc++) {
            qfA[kc] = *(const bf16x8_t*)(qa + kc * 32 + quad * 8);
            qfB[kc] = *(const bf16x8_t*)(qbp + kc * 32 + quad * 8);
        }
    }

    f32x4_t zero = {0.f, 0.f, 0.f, 0.f};
    f32x4_t oA[4], oB[4];
    float lA[4], lB[4];
#pragma unroll
    for (int c = 0; c < 4; c++) { oA[c] = zero; oB[c] = zero; }
#pragma unroll
    for (int i = 0; i < 4; i++) { lA[i] = 0.f; lB[i] = 0.f; }

    // prologue: stage kt=0 into buffer 0
    __builtin_amdgcn_global_load_lds(AS1C(kbase + rgK0), AS3(&Kbuf[0][0] + ldsc0), 16, 0, 0);
    __builtin_amdgcn_global_load_lds(AS1C(kbase + rgK1), AS3(&Kbuf[0][0] + ldsc1), 16, 0, 0);
    __builtin_amdgcn_global_load_lds(AS1C(vbase + rgV0), AS3(&Vbuf[0][0] + ldsc0), 16, 0, 0);
    __builtin_amdgcn_global_load_lds(AS1C(vbase + rgV1), AS3(&Vbuf[0][0] + ldsc1), 16, 0, 0);
    __syncthreads();

    for (int kt = 0; kt <= kmax; kt++) {
        const int cur = kt & 1, nxt = cur ^ 1;
        if (kt < kmax) {   // async prefetch kt+1 into nxt (completion enforced by barrier)
            const unsigned short* kp = kbase + (kt + 1) * 4096;
            const unsigned short* vp = vbase + (kt + 1) * 64;
            __builtin_amdgcn_global_load_lds(AS1C(kp + rgK0), AS3(&Kbuf[nxt][0] + ldsc0), 16, 0, 0);
            __builtin_amdgcn_global_load_lds(AS1C(kp + rgK1), AS3(&Kbuf[nxt][0] + ldsc1), 16, 0, 0);
            __builtin_amdgcn_global_load_lds(AS1C(vp + rgV0), AS3(&Vbuf[nxt][0] + ldsc0), 16, 0, 0);
            __builtin_amdgcn_global_load_lds(AS1C(vp + rgV1), AS3(&Vbuf[nxt][0] + ldsc1), 16, 0, 0);
        }

        bf16x8_t kf[4][2], vf[4][2];
        const unsigned short* Kc = &Kbuf[cur][0];
        const unsigned short* Vc = &Vbuf[cur][0];
#pragma unroll
        for (int c = 0; c < 4; c++)
#pragma unroll
            for (int kc = 0; kc < 2; kc++) {
                int roff = (c * 16 + l16) * 64 + (((kc * 4 + quad) ^ (l16 & 7)) << 3);
                kf[c][kc] = *(const bf16x8_t*)(Kc + roff);
                vf[c][kc] = *(const bf16x8_t*)(Vc + roff);
            }

        unsigned short* pw = &Psh[wv][0];
        attn_tile(qfB, kf, vf, oB, lB, pw, kt == tB, wv, quad, l16);
        if (kt <= t)
            attn_tile(qfA, kf, vf, oA, lA, pw, kt == t, wv, quad, l16);
        __syncthreads();
    }

    // deferred l reduction across the 16 lanes sharing quad
#pragma unroll
    for (int off = 1; off < 16; off <<= 1)
#pragma unroll
        for (int i = 0; i < 4; i++) {
            lA[i] += __shfl_xor(lA[i], off);
            lB[i] += __shfl_xor(lB[i], off);
        }
    float iA[4], iB[4];
#pragma unroll
    for (int i = 0; i < 4; i++) { iA[i] = 1.f / lA[i]; iB[i] = 1.f / lB[i]; }

#pragma unroll
    for (int c = 0; c < 4; c++)
#pragma unroll
        for (int i = 0; i < 4; i++) {
            int rowA = t * 64 + wv * 16 + quad * 4 + i;
            int rowB = tB * 64 + wv * 16 + quad * 4 + i;
            int col = h * HDIM + c * 16 + l16;
            attb[((size_t)b * SEQ_T + rowA) * CDIM + col] = f2bf(oA[c][i] * iA[i]);
            attb[((size_t)b * SEQ_T + rowB) * CDIM + col] = f2bf(oB[c][i] * iB[i]);
        }
}

// GEMM2: out(fp32) = att @ w_proj + b_proj
__global__ __launch_bounds__(256) void gemm_proj(
    const unsigned short* __restrict__ attb, const unsigned short* __restrict__ wpT,
    const float* __restrict__ b_proj, float* __restrict__ out)
{
    __shared__ __align__(16) unsigned short As[128 * 64];
    __shared__ __align__(16) unsigned short Bs[128 * 64];
    f32x4_t acc[4][4];
    const int mBase = blockIdx.y * 128;
    const int nBase = blockIdx.x * 128;
    gemm128_core(attb, wpT, As, Bs, acc, mBase, nBase);

    const int tid = threadIdx.x;
    const int lane = tid & 63, wv = tid >> 6;
    const int quad = lane >> 4, l16 = lane & 15;
    const int wm = (wv >> 1) * 64, wn = (wv & 1) * 64;

#pragma unroll
    for (int tn = 0; tn < 4; tn++) {
        int n = nBase + wn + tn * 16 + l16;
        float bv = b_proj[n];
#pragma unroll
        for (int tm = 0; tm < 4; tm++)
#pragma unroll
            for (int i = 0; i < 4; i++) {
                int row = mBase + wm + tm * 16 + quad * 4 + i;
                out[(size_t)row * CDIM + n] = acc[tm][tn][i] + bv;
            }
    }
}

extern "C" void kernel_launch(void* const* d_in, const int* in_sizes, int n_in,
                              void* d_out, int out_size, void* d_ws, size_t ws_size,
                              hipStream_t stream) {
    const float* x      = (const float*)d_in[0];  // [8,1024,768] fp32
    const float* w_attn = (const float*)d_in[1];  // [768,2304]   fp32
    const float* b_attn = (const float*)d_in[2];  // [2304]       fp32
    const float* w_proj = (const float*)d_in[3];  // [768,768]    fp32
    const float* b_proj = (const float*)d_in[4];  // [768]        fp32
    float* out = (float*)d_out;                   // [8,1024,768] fp32

    unsigned short* ws   = (unsigned short*)d_ws;
    unsigned short* waT  = ws;                    // 1,769,472  [2304][768] bf16
    unsigned short* wpT  = waT + 1769472;         //   589,824  [768][768]  bf16
    unsigned short* xbf  = wpT + 589824;          // 6,291,456  [8192][768] bf16
    unsigned short* qbuf = xbf + 6291456;         // 6,291,456  [B,H,T,D] (log2e-scaled)
    unsigned short* kbuf = qbuf + 6291456;        // 6,291,456  [B,H,T,D]
    unsigned short* vbuf = kbuf + 6291456;        // 6,291,456  [B,H,D,T]
    unsigned short* attb = vbuf + 6291456;        // 6,291,456  [B,T,C]
    // ws use: 67,633,152 bytes

    cvt_x<<<dim3(6144), 256, 0, stream>>>((const float4*)x, (ushort4*)xbf, 1572864);
    cvt_transpose<<<dim3(72, 24), dim3(32, 8), 0, stream>>>(w_attn, waT, 768, 2304);
    cvt_transpose<<<dim3(24, 24), dim3(32, 8), 0, stream>>>(w_proj, wpT, 768, 768);
    gemm_qkv<<<dim3(18, 64), 256, 0, stream>>>(xbf, waT, b_attn, qbuf, kbuf, vbuf);
    attn_fused<<<dim3(8, N_HEAD, 8), 256, 0, stream>>>(qbuf, kbuf, vbuf, attb);
    gemm_proj<<<dim3(6, 64), 256, 0, stream>>>(attb, wpT, b_proj, out);
}

// Round 5
// 199.417 us; speedup vs baseline: 1.6757x; 1.0634x over previous
//
#include <hip/hip_runtime.h>

typedef __attribute__((ext_vector_type(8))) short bf16x8_t;
typedef __attribute__((ext_vector_type(4))) float f32x4_t;

#define AS1C(p) ((const __attribute__((address_space(1))) void*)(p))
#define AS3(p)  ((__attribute__((address_space(3))) void*)(p))

#define N_HEAD 12
#define SEQ_T 1024
#define CDIM 768
#define HDIM 64
#define L2E 1.44269504f

__device__ __forceinline__ unsigned short f2bf(float f) {
    union { float f; unsigned int u; } v;
    v.f = f;
    unsigned int r = (v.u + 0x7fffu + ((v.u >> 16) & 1u)) >> 16;
    return (unsigned short)r;
}

// x fp32 -> bf16, vectorized
__global__ __launch_bounds__(256) void cvt_x(
    const float4* __restrict__ src, ushort4* __restrict__ dst, int n4)
{
    int i = blockIdx.x * 256 + threadIdx.x;
    if (i < n4) {
        float4 v = src[i];
        ushort4 o;
        o.x = f2bf(v.x); o.y = f2bf(v.y); o.z = f2bf(v.z); o.w = f2bf(v.w);
        dst[i] = o;
    }
}

// dst[c*R + r] = bf16(src[r*Cc + c]); LDS-tiled. grid (Cc/32, R/32), block (32,8)
__global__ __launch_bounds__(256) void cvt_transpose(
    const float* __restrict__ src, unsigned short* __restrict__ dst, int R, int Cc)
{
    __shared__ float tile[32][33];
    int c0 = blockIdx.x * 32, r0 = blockIdx.y * 32;
#pragma unroll
    for (int i = 0; i < 4; i++)
        tile[threadIdx.y + i * 8][threadIdx.x] =
            src[(size_t)(r0 + threadIdx.y + i * 8) * Cc + c0 + threadIdx.x];
    __syncthreads();
#pragma unroll
    for (int i = 0; i < 4; i++)
        dst[(size_t)(c0 + threadIdx.y + i * 8) * R + r0 + threadIdx.x] =
            f2bf(tile[threadIdx.x][threadIdx.y + i * 8]);
}

// 128x128 tile GEMM core, K=768. Async width-16 staging + XOR-granule LDS swizzle:
// LDS granule position p of row r holds global granule p^(r&7) -> 2-way banks on read.
__device__ __forceinline__ void gemm128_core(
    const unsigned short* __restrict__ A, const unsigned short* __restrict__ Bt,
    unsigned short* As, unsigned short* Bs, f32x4_t acc[4][4], int mBase, int nBase)
{
    const int tid  = threadIdx.x;
    const int lane = tid & 63;
    const int wv   = tid >> 6;
    const int quad = lane >> 4;
    const int l16  = lane & 15;
    const int wm   = (wv >> 1) * 64;
    const int wn   = (wv & 1) * 64;

    f32x4_t zero = {0.f, 0.f, 0.f, 0.f};
#pragma unroll
    for (int tm = 0; tm < 4; tm++)
#pragma unroll
        for (int tn = 0; tn < 4; tn++)
            acc[tm][tn] = zero;

    for (int kt = 0; kt < 768; kt += 64) {
#pragma unroll
        for (int i = 0; i < 4; i++) {
            int cbase = i * 256 + wv * 64;       // wave-uniform chunk base
            int ci = cbase + lane;               // 16B chunk 0..1023
            int r = ci >> 3;
            int koff = (((ci & 7) ^ (r & 7)) << 3);   // swizzled granule
            __builtin_amdgcn_global_load_lds(
                AS1C(A + (size_t)(mBase + r) * 768 + kt + koff),
                AS3(As + cbase * 8), 16, 0, 0);
            __builtin_amdgcn_global_load_lds(
                AS1C(Bt + (size_t)(nBase + r) * 768 + kt + koff),
                AS3(Bs + cbase * 8), 16, 0, 0);
        }
        __syncthreads();
#pragma unroll
        for (int ks = 0; ks < 2; ks++) {
            bf16x8_t af[4], bfv[4];
#pragma unroll
            for (int tm = 0; tm < 4; tm++)
                af[tm] = *(const bf16x8_t*)(As + (wm + tm * 16 + l16) * 64 +
                                            (((ks * 4 + quad) ^ (l16 & 7)) << 3));
#pragma unroll
            for (int tn = 0; tn < 4; tn++)
                bfv[tn] = *(const bf16x8_t*)(Bs + (wn + tn * 16 + l16) * 64 +
                                             (((ks * 4 + quad) ^ (l16 & 7)) << 3));
#pragma unroll
            for (int tm = 0; tm < 4; tm++)
#pragma unroll
                for (int tn = 0; tn < 4; tn++)
                    acc[tm][tn] = __builtin_amdgcn_mfma_f32_16x16x32_bf16(
                        af[tm], bfv[tn], acc[tm][tn], 0, 0, 0);
        }
        __syncthreads();
    }
}

// GEMM1: qkv = x @ w_attn + b_attn; q scaled by log2e; q,k -> [B,H,T,D], v -> [B,H,D,T]
__global__ __launch_bounds__(256) void gemm_qkv(
    const unsigned short* __restrict__ x, const unsigned short* __restrict__ waT,
    const float* __restrict__ b_attn,
    unsigned short* __restrict__ qbuf, unsigned short* __restrict__ kbuf,
    unsigned short* __restrict__ vbuf)
{
    __shared__ __align__(16) unsigned short As[128 * 64];
    __shared__ __align__(16) unsigned short Bs[128 * 64];
    f32x4_t acc[4][4];
    const int mBase = blockIdx.y * 128;
    const int nBase = blockIdx.x * 128;
    gemm128_core(x, waT, As, Bs, acc, mBase, nBase);

    const int tid = threadIdx.x;
    const int lane = tid & 63, wv = tid >> 6;
    const int quad = lane >> 4, l16 = lane & 15;
    const int wm = (wv >> 1) * 64, wn = (wv & 1) * 64;
    const int part = blockIdx.x / 6;    // 0=q 1=k 2=v (block-uniform)

#pragma unroll
    for (int tn = 0; tn < 4; tn++) {
        int n = nBase + wn + tn * 16 + l16;     // 0..2303
        float bv = b_attn[n];
        int f = n - part * 768;
        int hh = f >> 6, d = f & 63;
        if (part == 2) {
#pragma unroll
            for (int tm = 0; tm < 4; tm++) {
                int t0 = mBase + wm + tm * 16 + quad * 4;   // 4-aligned, no b-crossing
                int bb = t0 >> 10, tt = t0 & 1023;
                ushort4 pk;
                pk.x = f2bf(acc[tm][tn][0] + bv);
                pk.y = f2bf(acc[tm][tn][1] + bv);
                pk.z = f2bf(acc[tm][tn][2] + bv);
                pk.w = f2bf(acc[tm][tn][3] + bv);
                *(ushort4*)(vbuf + ((size_t)(bb * N_HEAD + hh) * HDIM + d) * SEQ_T + tt) = pk;
            }
        } else {
            const float scale = (part == 0) ? L2E : 1.f;
            unsigned short* dst = (part == 0) ? qbuf : kbuf;
#pragma unroll
            for (int tm = 0; tm < 4; tm++) {
#pragma unroll
                for (int i = 0; i < 4; i++) {
                    int row = mBase + wm + tm * 16 + quad * 4 + i;
                    int bb = row >> 10, tt = row & 1023;
                    dst[((size_t)(bb * N_HEAD + hh) * SEQ_T + tt) * HDIM + d] =
                        f2bf((acc[tm][tn][i] + bv) * scale);
                }
            }
        }
    }
}

// softmax + PV for one tile, S^T form. s[c][i] holds S^T[s=c*16+quad*4+i][q=l16].
// P emerges s-contiguous per lane -> packed b32 LDS writes, b128 A-frag reads.
__device__ __forceinline__ void attn_pv(
    f32x4_t s[4], int diag, int qloc, int quad, int l16,
    float& lsum, unsigned short* pw, const bf16x8_t vf[4][2], f32x4_t o[4])
{
    if (diag) {
#pragma unroll
        for (int c = 0; c < 4; c++)
#pragma unroll
            for (int i = 0; i < 4; i++)
                if (c * 16 + quad * 4 + i > qloc) s[c][i] = -1e30f;
    }
    float p[4][4];
#pragma unroll
    for (int c = 0; c < 4; c++)
#pragma unroll
        for (int i = 0; i < 4; i++)
            p[c][i] = exp2f(s[c][i]);
#pragma unroll
    for (int c = 0; c < 4; c++)
        lsum += (p[c][0] + p[c][1]) + (p[c][2] + p[c][3]);

    unsigned int u[4][2];
#pragma unroll
    for (int c = 0; c < 4; c++)
#pragma unroll
        for (int i2 = 0; i2 < 2; i2++)
            u[c][i2] = (unsigned int)f2bf(p[c][2 * i2]) |
                       ((unsigned int)f2bf(p[c][2 * i2 + 1]) << 16);

    // per-wave LDS region; same-wave DS ops are in-order -> only compiler fences needed
    __asm__ __volatile__("" ::: "memory");
#pragma unroll
    for (int c = 0; c < 4; c++)
#pragma unroll
        for (int i2 = 0; i2 < 2; i2++) {
            int g = c * 2 + (quad >> 1);
            *(unsigned int*)(pw + l16 * 64 + ((g ^ (l16 & 7)) << 3) +
                             4 * (quad & 1) + 2 * i2) = u[c][i2];
        }
    __asm__ __volatile__("" ::: "memory");
    bf16x8_t pf[2];
#pragma unroll
    for (int kc = 0; kc < 2; kc++)
        pf[kc] = *(const bf16x8_t*)(pw + l16 * 64 + (((kc * 4 + quad) ^ (l16 & 7)) << 3));
    __asm__ __volatile__("" ::: "memory");
#pragma unroll
    for (int kc = 0; kc < 2; kc++)
#pragma unroll
        for (int nc = 0; nc < 4; nc++)
            o[nc] = __builtin_amdgcn_mfma_f32_16x16x32_bf16(pf[kc], vf[nc][kc], o[nc], 0, 0, 0);
}

// Fused causal attention. Block = paired q-tiles (t, 15-t): uniform 17 tile-iters.
// S^T = mfma(K-frag, Q-frag); per-lane scalar l accumulator; dbuf async K/V staging.
__global__ __launch_bounds__(256, 3) void attn_fused(
    const unsigned short* __restrict__ qb, const unsigned short* __restrict__ kb,
    const unsigned short* __restrict__ vb, unsigned short* __restrict__ attb)
{
    __shared__ __align__(16) unsigned short Kbuf[2][64 * 64];
    __shared__ __align__(16) unsigned short Vbuf[2][64 * 64];   // V^T tiles [d][s]
    __shared__ __align__(16) unsigned short Psh[4][16 * 64];

    const int t = blockIdx.x;       // 0..7; tiles t and 15-t
    const int h = blockIdx.y;
    const int b = blockIdx.z;
    const int tid = threadIdx.x;
    const int lane = tid & 63, wv = tid >> 6;
    const int quad = lane >> 4, l16 = lane & 15;
    const int tB = 15 - t, kmax = 15 - t;
    const int qloc = wv * 16 + l16;

    const size_t bh = (size_t)(b * N_HEAD + h);
    const unsigned short* kbase = kb + bh * SEQ_T * HDIM;
    const unsigned short* vbase = vb + bh * HDIM * SEQ_T;
    const unsigned short* qpt   = qb + bh * SEQ_T * HDIM;

    // staging: 512 16B chunks per buffer; LDS side lane-contiguous; global side
    // granule-permuted (g ^= r&7)
    const int j0 = wv * 128 + lane, j1 = j0 + 64;
    const int r0 = j0 >> 3, g0 = (j0 & 7) ^ (r0 & 7);
    const int r1 = j1 >> 3, g1 = (j1 & 7) ^ (r1 & 7);
    const int rgK0 = r0 * 64 + g0 * 8,   rgK1 = r1 * 64 + g1 * 8;
    const int rgV0 = r0 * 1024 + g0 * 8, rgV1 = r1 * 1024 + g1 * 8;
    const int ldsc0 = (wv * 128) * 8, ldsc1 = (wv * 128 + 64) * 8;  // wave-uniform

    bf16x8_t qfA[2], qfB[2];
    {
        const unsigned short* qa  = qpt + (size_t)(t * 64 + qloc) * HDIM;
        const unsigned short* qbp = qpt + (size_t)(tB * 64 + qloc) * HDIM;
#pragma unroll
        for (int kc = 0; kc < 2; kc++) {
            qfA[kc] = *(const bf16x8_t*)(qa + kc * 32 + quad * 8);
            qfB[kc] = *(const bf16x8_t*)(qbp + kc * 32 + quad * 8);
        }
    }

    f32x4_t zero = {0.f, 0.f, 0.f, 0.f};
    f32x4_t oA[4], oB[4];
#pragma unroll
    for (int c = 0; c < 4; c++) { oA[c] = zero; oB[c] = zero; }
    float lA = 0.f, lB = 0.f;

    __builtin_amdgcn_global_load_lds(AS1C(kbase + rgK0), AS3(&Kbuf[0][0] + ldsc0), 16, 0, 0);
    __builtin_amdgcn_global_load_lds(AS1C(kbase + rgK1), AS3(&Kbuf[0][0] + ldsc1), 16, 0, 0);
    __builtin_amdgcn_global_load_lds(AS1C(vbase + rgV0), AS3(&Vbuf[0][0] + ldsc0), 16, 0, 0);
    __builtin_amdgcn_global_load_lds(AS1C(vbase + rgV1), AS3(&Vbuf[0][0] + ldsc1), 16, 0, 0);
    __syncthreads();

    for (int kt = 0; kt <= kmax; kt++) {
        const int cur = kt & 1, nxt = cur ^ 1;
        if (kt < kmax) {
            const unsigned short* kp = kbase + (kt + 1) * 4096;
            const unsigned short* vp = vbase + (kt + 1) * 64;
            __builtin_amdgcn_global_load_lds(AS1C(kp + rgK0), AS3(&Kbuf[nxt][0] + ldsc0), 16, 0, 0);
            __builtin_amdgcn_global_load_lds(AS1C(kp + rgK1), AS3(&Kbuf[nxt][0] + ldsc1), 16, 0, 0);
            __builtin_amdgcn_global_load_lds(AS1C(vp + rgV0), AS3(&Vbuf[nxt][0] + ldsc0), 16, 0, 0);
            __builtin_amdgcn_global_load_lds(AS1C(vp + rgV1), AS3(&Vbuf[nxt][0] + ldsc1), 16, 0, 0);
        }

        const unsigned short* Kc = &Kbuf[cur][0];
        const unsigned short* Vc = &Vbuf[cur][0];
        const int doA = (kt <= t);

        // V B-frags (shared by both tiles)
        bf16x8_t vf[4][2];
#pragma unroll
        for (int nc = 0; nc < 4; nc++)
#pragma unroll
            for (int kc = 0; kc < 2; kc++)
                vf[nc][kc] = *(const bf16x8_t*)(Vc + (nc * 16 + l16) * 64 +
                                                (((kc * 4 + quad) ^ (l16 & 7)) << 3));

        // S^T: D[s][q] via mfma(A=K-frag, B=Q-frag)
        f32x4_t sB[4], sA[4];
#pragma unroll
        for (int c = 0; c < 4; c++) {
            bf16x8_t kf0 = *(const bf16x8_t*)(Kc + (c * 16 + l16) * 64 +
                                              ((quad ^ (l16 & 7)) << 3));
            bf16x8_t kf1 = *(const bf16x8_t*)(Kc + (c * 16 + l16) * 64 +
                                              (((4 + quad) ^ (l16 & 7)) << 3));
            sB[c] = __builtin_amdgcn_mfma_f32_16x16x32_bf16(kf0, qfB[0], zero, 0, 0, 0);
            sB[c] = __builtin_amdgcn_mfma_f32_16x16x32_bf16(kf1, qfB[1], sB[c], 0, 0, 0);
            if (doA) {
                sA[c] = __builtin_amdgcn_mfma_f32_16x16x32_bf16(kf0, qfA[0], zero, 0, 0, 0);
                sA[c] = __builtin_amdgcn_mfma_f32_16x16x32_bf16(kf1, qfA[1], sA[c], 0, 0, 0);
            }
        }

        unsigned short* pw = &Psh[wv][0];
        attn_pv(sB, kt == tB, qloc, quad, l16, lB, pw, vf, oB);
        if (doA)
            attn_pv(sA, kt == t, qloc, quad, l16, lA, pw, vf, oA);
        __syncthreads();
    }

    // l reduction: per-lane partials -> total over s for q=l16 (xor across quads)
    lA += __shfl_xor(lA, 16); lA += __shfl_xor(lA, 32);
    lB += __shfl_xor(lB, 16); lB += __shfl_xor(lB, 32);
    float invA = 1.f / lA, invB = 1.f / lB;
    // O rows are q=quad*4+i; fetch matching 1/l via bpermute
    float iA[4], iB[4];
#pragma unroll
    for (int i = 0; i < 4; i++) {
        iA[i] = __shfl(invA, quad * 4 + i);
        iB[i] = __shfl(invB, quad * 4 + i);
    }

#pragma unroll
    for (int nc = 0; nc < 4; nc++)
#pragma unroll
        for (int i = 0; i < 4; i++) {
            int rowA = t * 64 + wv * 16 + quad * 4 + i;
            int rowB = tB * 64 + wv * 16 + quad * 4 + i;
            int col = h * HDIM + nc * 16 + l16;
            attb[((size_t)b * SEQ_T + rowA) * CDIM + col] = f2bf(oA[nc][i] * iA[i]);
            attb[((size_t)b * SEQ_T + rowB) * CDIM + col] = f2bf(oB[nc][i] * iB[i]);
        }
}

// GEMM2: out(fp32) = att @ w_proj + b_proj
__global__ __launch_bounds__(256) void gemm_proj(
    const unsigned short* __restrict__ attb, const unsigned short* __restrict__ wpT,
    const float* __restrict__ b_proj, float* __restrict__ out)
{
    __shared__ __align__(16) unsigned short As[128 * 64];
    __shared__ __align__(16) unsigned short Bs[128 * 64];
    f32x4_t acc[4][4];
    const int mBase = blockIdx.y * 128;
    const int nBase = blockIdx.x * 128;
    gemm128_core(attb, wpT, As, Bs, acc, mBase, nBase);

    const int tid = threadIdx.x;
    const int lane = tid & 63, wv = tid >> 6;
    const int quad = lane >> 4, l16 = lane & 15;
    const int wm = (wv >> 1) * 64, wn = (wv & 1) * 64;

#pragma unroll
    for (int tn = 0; tn < 4; tn++) {
        int n = nBase + wn + tn * 16 + l16;
        float bv = b_proj[n];
#pragma unroll
        for (int tm = 0; tm < 4; tm++)
#pragma unroll
            for (int i = 0; i < 4; i++) {
                int row = mBase + wm + tm * 16 + quad * 4 + i;
                out[(size_t)row * CDIM + n] = acc[tm][tn][i] + bv;
            }
    }
}

extern "C" void kernel_launch(void* const* d_in, const int* in_sizes, int n_in,
                              void* d_out, int out_size, void* d_ws, size_t ws_size,
                              hipStream_t stream) {
    const float* x      = (const float*)d_in[0];  // [8,1024,768] fp32
    const float* w_attn = (const float*)d_in[1];  // [768,2304]   fp32
    const float* b_attn = (const float*)d_in[2];  // [2304]       fp32
    const float* w_proj = (const float*)d_in[3];  // [768,768]    fp32
    const float* b_proj = (const float*)d_in[4];  // [768]        fp32
    float* out = (float*)d_out;                   // [8,1024,768] fp32

    unsigned short* ws   = (unsigned short*)d_ws;
    unsigned short* waT  = ws;                    // 1,769,472  [2304][768] bf16
    unsigned short* wpT  = waT + 1769472;         //   589,824  [768][768]  bf16
    unsigned short* xbf  = wpT + 589824;          // 6,291,456  [8192][768] bf16
    unsigned short* qbuf = xbf + 6291456;         // [B,H,T,D] (log2e-scaled)
    unsigned short* kbuf = qbuf + 6291456;        // [B,H,T,D]
    unsigned short* vbuf = kbuf + 6291456;        // [B,H,D,T]
    unsigned short* attb = vbuf + 6291456;        // [B,T,C]
    // ws use: 67,633,152 bytes

    cvt_x<<<dim3(6144), 256, 0, stream>>>((const float4*)x, (ushort4*)xbf, 1572864);
    cvt_transpose<<<dim3(72, 24), dim3(32, 8), 0, stream>>>(w_attn, waT, 768, 2304);
    cvt_transpose<<<dim3(24, 24), dim3(32, 8), 0, stream>>>(w_proj, wpT, 768, 768);
    gemm_qkv<<<dim3(18, 64), 256, 0, stream>>>(xbf, waT, b_attn, qbuf, kbuf, vbuf);
    attn_fused<<<dim3(8, N_HEAD, 8), 256, 0, stream>>>(qbuf, kbuf, vbuf, attb);
    gemm_proj<<<dim3(6, 64), 256, 0, stream>>>(attb, wpT, b_proj, out);
}

// Round 6
// 192.448 us; speedup vs baseline: 1.7364x; 1.0362x over previous
//
#include <hip/hip_runtime.h>

typedef __attribute__((ext_vector_type(8))) short bf16x8_t;
typedef __attribute__((ext_vector_type(4))) float f32x4_t;

#define AS1C(p) ((const __attribute__((address_space(1))) void*)(p))
#define AS3(p)  ((__attribute__((address_space(3))) void*)(p))

#define N_HEAD 12
#define SEQ_T 1024
#define CDIM 768
#define HDIM 64
#define L2E 1.44269504f

__device__ __forceinline__ unsigned short f2bf(float f) {
    union { float f; unsigned int u; } v;
    v.f = f;
    unsigned int r = (v.u + 0x7fffu + ((v.u >> 16) & 1u)) >> 16;
    return (unsigned short)r;
}

// x fp32 -> bf16, vectorized
__global__ __launch_bounds__(256) void cvt_x(
    const float4* __restrict__ src, ushort4* __restrict__ dst, int n4)
{
    int i = blockIdx.x * 256 + threadIdx.x;
    if (i < n4) {
        float4 v = src[i];
        ushort4 o;
        o.x = f2bf(v.x); o.y = f2bf(v.y); o.z = f2bf(v.z); o.w = f2bf(v.w);
        dst[i] = o;
    }
}

// dst[c*R + r] = bf16(src[r*Cc + c]); LDS-tiled. grid (Cc/32, R/32), block (32,8)
__global__ __launch_bounds__(256) void cvt_transpose(
    const float* __restrict__ src, unsigned short* __restrict__ dst, int R, int Cc)
{
    __shared__ float tile[32][33];
    int c0 = blockIdx.x * 32, r0 = blockIdx.y * 32;
#pragma unroll
    for (int i = 0; i < 4; i++)
        tile[threadIdx.y + i * 8][threadIdx.x] =
            src[(size_t)(r0 + threadIdx.y + i * 8) * Cc + c0 + threadIdx.x];
    __syncthreads();
#pragma unroll
    for (int i = 0; i < 4; i++)
        dst[(size_t)(c0 + threadIdx.y + i * 8) * R + r0 + threadIdx.x] =
            f2bf(tile[threadIdx.x][threadIdx.y + i * 8]);
}

// 128x128 tile GEMM core, K=768. Async width-16 staging + XOR-granule LDS swizzle.
__device__ __forceinline__ void gemm128_core(
    const unsigned short* __restrict__ A, const unsigned short* __restrict__ Bt,
    unsigned short* As, unsigned short* Bs, f32x4_t acc[4][4], int mBase, int nBase)
{
    const int tid  = threadIdx.x;
    const int lane = tid & 63;
    const int wv   = tid >> 6;
    const int quad = lane >> 4;
    const int l16  = lane & 15;
    const int wm   = (wv >> 1) * 64;
    const int wn   = (wv & 1) * 64;

    f32x4_t zero = {0.f, 0.f, 0.f, 0.f};
#pragma unroll
    for (int tm = 0; tm < 4; tm++)
#pragma unroll
        for (int tn = 0; tn < 4; tn++)
            acc[tm][tn] = zero;

    for (int kt = 0; kt < 768; kt += 64) {
#pragma unroll
        for (int i = 0; i < 4; i++) {
            int cbase = i * 256 + wv * 64;       // wave-uniform chunk base
            int ci = cbase + lane;               // 16B chunk 0..1023
            int r = ci >> 3;
            int koff = (((ci & 7) ^ (r & 7)) << 3);   // swizzled granule
            __builtin_amdgcn_global_load_lds(
                AS1C(A + (size_t)(mBase + r) * 768 + kt + koff),
                AS3(As + cbase * 8), 16, 0, 0);
            __builtin_amdgcn_global_load_lds(
                AS1C(Bt + (size_t)(nBase + r) * 768 + kt + koff),
                AS3(Bs + cbase * 8), 16, 0, 0);
        }
        __syncthreads();
#pragma unroll
        for (int ks = 0; ks < 2; ks++) {
            bf16x8_t af[4], bfv[4];
#pragma unroll
            for (int tm = 0; tm < 4; tm++)
                af[tm] = *(const bf16x8_t*)(As + (wm + tm * 16 + l16) * 64 +
                                            (((ks * 4 + quad) ^ (l16 & 7)) << 3));
#pragma unroll
            for (int tn = 0; tn < 4; tn++)
                bfv[tn] = *(const bf16x8_t*)(Bs + (wn + tn * 16 + l16) * 64 +
                                             (((ks * 4 + quad) ^ (l16 & 7)) << 3));
#pragma unroll
            for (int tm = 0; tm < 4; tm++)
#pragma unroll
                for (int tn = 0; tn < 4; tn++)
                    acc[tm][tn] = __builtin_amdgcn_mfma_f32_16x16x32_bf16(
                        af[tm], bfv[tn], acc[tm][tn], 0, 0, 0);
        }
        __syncthreads();
    }
}

// GEMM1: qkv = x @ w_attn + b_attn. 1D grid 1152, XCD-sliced: xcd = lid&7 owns
// m-tiles [xcd*8, xcd*8+8) x all n -> A-slice (1.6 MB) stays in that XCD's L2.
__global__ __launch_bounds__(256) void gemm_qkv(
    const unsigned short* __restrict__ x, const unsigned short* __restrict__ waT,
    const float* __restrict__ b_attn,
    unsigned short* __restrict__ qbuf, unsigned short* __restrict__ kbuf,
    unsigned short* __restrict__ vbuf)
{
    __shared__ __align__(16) unsigned short As[128 * 64];
    __shared__ __align__(16) unsigned short Bs[128 * 64];
    f32x4_t acc[4][4];
    const int lid = blockIdx.x;
    const int xcd = lid & 7;
    const int j = lid >> 3;                 // 0..143
    const int mTile = xcd * 8 + (j & 7);    // 0..63
    const int nTile = j >> 3;               // 0..17
    const int mBase = mTile * 128;
    const int nBase = nTile * 128;
    gemm128_core(x, waT, As, Bs, acc, mBase, nBase);

    const int tid = threadIdx.x;
    const int lane = tid & 63, wv = tid >> 6;
    const int quad = lane >> 4, l16 = lane & 15;
    const int wm = (wv >> 1) * 64, wn = (wv & 1) * 64;
    const int part = nTile / 6;             // 0=q 1=k 2=v (block-uniform)

#pragma unroll
    for (int tn = 0; tn < 4; tn++) {
        int n = nBase + wn + tn * 16 + l16;     // 0..2303
        float bv = b_attn[n];
        int f = n - part * 768;
        int hh = f >> 6, d = f & 63;
        if (part == 2) {
#pragma unroll
            for (int tm = 0; tm < 4; tm++) {
                int t0 = mBase + wm + tm * 16 + quad * 4;   // 4-aligned, no b-crossing
                int bb = t0 >> 10, tt = t0 & 1023;
                ushort4 pk;
                pk.x = f2bf(acc[tm][tn][0] + bv);
                pk.y = f2bf(acc[tm][tn][1] + bv);
                pk.z = f2bf(acc[tm][tn][2] + bv);
                pk.w = f2bf(acc[tm][tn][3] + bv);
                *(ushort4*)(vbuf + ((size_t)(bb * N_HEAD + hh) * HDIM + d) * SEQ_T + tt) = pk;
            }
        } else {
            const float scale = (part == 0) ? L2E : 1.f;
            unsigned short* dst = (part == 0) ? qbuf : kbuf;
#pragma unroll
            for (int tm = 0; tm < 4; tm++) {
#pragma unroll
                for (int i = 0; i < 4; i++) {
                    int row = mBase + wm + tm * 16 + quad * 4 + i;
                    int bb = row >> 10, tt = row & 1023;
                    dst[((size_t)(bb * N_HEAD + hh) * SEQ_T + tt) * HDIM + d] =
                        f2bf((acc[tm][tn][i] + bv) * scale);
                }
            }
        }
    }
}

// softmax + PV for one tile, S^T form. s[c][i] holds S^T[s=c*16+quad*4+i][q=l16].
__device__ __forceinline__ void attn_pv(
    f32x4_t s[4], int diag, int qloc, int quad, int l16,
    float& lsum, unsigned short* pw, const bf16x8_t vf[4][2], f32x4_t o[4])
{
    if (diag) {
#pragma unroll
        for (int c = 0; c < 4; c++)
#pragma unroll
            for (int i = 0; i < 4; i++)
                if (c * 16 + quad * 4 + i > qloc) s[c][i] = -1e30f;
    }
    float p[4][4];
#pragma unroll
    for (int c = 0; c < 4; c++)
#pragma unroll
        for (int i = 0; i < 4; i++)
            p[c][i] = exp2f(s[c][i]);
#pragma unroll
    for (int c = 0; c < 4; c++)
        lsum += (p[c][0] + p[c][1]) + (p[c][2] + p[c][3]);

    unsigned int u[4][2];
#pragma unroll
    for (int c = 0; c < 4; c++)
#pragma unroll
        for (int i2 = 0; i2 < 2; i2++)
            u[c][i2] = (unsigned int)f2bf(p[c][2 * i2]) |
                       ((unsigned int)f2bf(p[c][2 * i2 + 1]) << 16);

    __asm__ __volatile__("" ::: "memory");
#pragma unroll
    for (int c = 0; c < 4; c++)
#pragma unroll
        for (int i2 = 0; i2 < 2; i2++) {
            int g = c * 2 + (quad >> 1);
            *(unsigned int*)(pw + l16 * 64 + ((g ^ (l16 & 7)) << 3) +
                             4 * (quad & 1) + 2 * i2) = u[c][i2];
        }
    __asm__ __volatile__("" ::: "memory");
    bf16x8_t pf[2];
#pragma unroll
    for (int kc = 0; kc < 2; kc++)
        pf[kc] = *(const bf16x8_t*)(pw + l16 * 64 + (((kc * 4 + quad) ^ (l16 & 7)) << 3));
    __asm__ __volatile__("" ::: "memory");
#pragma unroll
    for (int kc = 0; kc < 2; kc++)
#pragma unroll
        for (int nc = 0; nc < 4; nc++)
            o[nc] = __builtin_amdgcn_mfma_f32_16x16x32_bf16(pf[kc], vf[nc][kc], o[nc], 0, 0, 0);
}

// Fused causal attention. Block = paired q-tiles (t, 15-t). Grid (96 bh, 8 t):
// lid = bh + 96*t -> lid%8 = bh%8, so all 8 pair-blocks of a (b,h) share one XCD
// and its K/V (256 KB) stays in that XCD's L2.
__global__ __launch_bounds__(256, 3) void attn_fused(
    const unsigned short* __restrict__ qb, const unsigned short* __restrict__ kb,
    const unsigned short* __restrict__ vb, unsigned short* __restrict__ attb)
{
    __shared__ __align__(16) unsigned short Kbuf[2][64 * 64];
    __shared__ __align__(16) unsigned short Vbuf[2][64 * 64];   // V^T tiles [d][s]
    __shared__ __align__(16) unsigned short Psh[4][16 * 64];

    const int bhx = blockIdx.x;     // 0..95
    const int t   = blockIdx.y;     // 0..7; tiles t and 15-t
    const int h = bhx % N_HEAD;
    const int b = bhx / N_HEAD;
    const int tid = threadIdx.x;
    const int lane = tid & 63, wv = tid >> 6;
    const int quad = lane >> 4, l16 = lane & 15;
    const int tB = 15 - t, kmax = 15 - t;
    const int qloc = wv * 16 + l16;

    const size_t bh = (size_t)(b * N_HEAD + h);
    const unsigned short* kbase = kb + bh * SEQ_T * HDIM;
    const unsigned short* vbase = vb + bh * HDIM * SEQ_T;
    const unsigned short* qpt   = qb + bh * SEQ_T * HDIM;

    const int j0 = wv * 128 + lane, j1 = j0 + 64;
    const int r0 = j0 >> 3, g0 = (j0 & 7) ^ (r0 & 7);
    const int r1 = j1 >> 3, g1 = (j1 & 7) ^ (r1 & 7);
    const int rgK0 = r0 * 64 + g0 * 8,   rgK1 = r1 * 64 + g1 * 8;
    const int rgV0 = r0 * 1024 + g0 * 8, rgV1 = r1 * 1024 + g1 * 8;
    const int ldsc0 = (wv * 128) * 8, ldsc1 = (wv * 128 + 64) * 8;  // wave-uniform

    bf16x8_t qfA[2], qfB[2];
    {
        const unsigned short* qa  = qpt + (size_t)(t * 64 + qloc) * HDIM;
        const unsigned short* qbp = qpt + (size_t)(tB * 64 + qloc) * HDIM;
#pragma unroll
        for (int kc = 0; kc < 2; kc++) {
            qfA[kc] = *(const bf16x8_t*)(qa + kc * 32 + quad * 8);
            qfB[kc] = *(const bf16x8_t*)(qbp + kc * 32 + quad * 8);
        }
    }

    f32x4_t zero = {0.f, 0.f, 0.f, 0.f};
    f32x4_t oA[4], oB[4];
#pragma unroll
    for (int c = 0; c < 4; c++) { oA[c] = zero; oB[c] = zero; }
    float lA = 0.f, lB = 0.f;

    __builtin_amdgcn_global_load_lds(AS1C(kbase + rgK0), AS3(&Kbuf[0][0] + ldsc0), 16, 0, 0);
    __builtin_amdgcn_global_load_lds(AS1C(kbase + rgK1), AS3(&Kbuf[0][0] + ldsc1), 16, 0, 0);
    __builtin_amdgcn_global_load_lds(AS1C(vbase + rgV0), AS3(&Vbuf[0][0] + ldsc0), 16, 0, 0);
    __builtin_amdgcn_global_load_lds(AS1C(vbase + rgV1), AS3(&Vbuf[0][0] + ldsc1), 16, 0, 0);
    __syncthreads();

    for (int kt = 0; kt <= kmax; kt++) {
        const int cur = kt & 1, nxt = cur ^ 1;
        if (kt < kmax) {
            const unsigned short* kp = kbase + (kt + 1) * 4096;
            const unsigned short* vp = vbase + (kt + 1) * 64;
            __builtin_amdgcn_global_load_lds(AS1C(kp + rgK0), AS3(&Kbuf[nxt][0] + ldsc0), 16, 0, 0);
            __builtin_amdgcn_global_load_lds(AS1C(kp + rgK1), AS3(&Kbuf[nxt][0] + ldsc1), 16, 0, 0);
            __builtin_amdgcn_global_load_lds(AS1C(vp + rgV0), AS3(&Vbuf[nxt][0] + ldsc0), 16, 0, 0);
            __builtin_amdgcn_global_load_lds(AS1C(vp + rgV1), AS3(&Vbuf[nxt][0] + ldsc1), 16, 0, 0);
        }

        const unsigned short* Kc = &Kbuf[cur][0];
        const unsigned short* Vc = &Vbuf[cur][0];
        const int doA = (kt <= t);

        bf16x8_t vf[4][2];
#pragma unroll
        for (int nc = 0; nc < 4; nc++)
#pragma unroll
            for (int kc = 0; kc < 2; kc++)
                vf[nc][kc] = *(const bf16x8_t*)(Vc + (nc * 16 + l16) * 64 +
                                                (((kc * 4 + quad) ^ (l16 & 7)) << 3));

        f32x4_t sB[4], sA[4];
#pragma unroll
        for (int c = 0; c < 4; c++) {
            bf16x8_t kf0 = *(const bf16x8_t*)(Kc + (c * 16 + l16) * 64 +
                                              ((quad ^ (l16 & 7)) << 3));
            bf16x8_t kf1 = *(const bf16x8_t*)(Kc + (c * 16 + l16) * 64 +
                                              (((4 + quad) ^ (l16 & 7)) << 3));
            sB[c] = __builtin_amdgcn_mfma_f32_16x16x32_bf16(kf0, qfB[0], zero, 0, 0, 0);
            sB[c] = __builtin_amdgcn_mfma_f32_16x16x32_bf16(kf1, qfB[1], sB[c], 0, 0, 0);
            if (doA) {
                sA[c] = __builtin_amdgcn_mfma_f32_16x16x32_bf16(kf0, qfA[0], zero, 0, 0, 0);
                sA[c] = __builtin_amdgcn_mfma_f32_16x16x32_bf16(kf1, qfA[1], sA[c], 0, 0, 0);
            }
        }

        unsigned short* pw = &Psh[wv][0];
        attn_pv(sB, kt == tB, qloc, quad, l16, lB, pw, vf, oB);
        if (doA)
            attn_pv(sA, kt == t, qloc, quad, l16, lA, pw, vf, oA);
        __syncthreads();
    }

    lA += __shfl_xor(lA, 16); lA += __shfl_xor(lA, 32);
    lB += __shfl_xor(lB, 16); lB += __shfl_xor(lB, 32);
    float invA = 1.f / lA, invB = 1.f / lB;
    float iA[4], iB[4];
#pragma unroll
    for (int i = 0; i < 4; i++) {
        iA[i] = __shfl(invA, quad * 4 + i);
        iB[i] = __shfl(invB, quad * 4 + i);
    }

#pragma unroll
    for (int nc = 0; nc < 4; nc++)
#pragma unroll
        for (int i = 0; i < 4; i++) {
            int rowA = t * 64 + wv * 16 + quad * 4 + i;
            int rowB = tB * 64 + wv * 16 + quad * 4 + i;
            int col = h * HDIM + nc * 16 + l16;
            attb[((size_t)b * SEQ_T + rowA) * CDIM + col] = f2bf(oA[nc][i] * iA[i]);
            attb[((size_t)b * SEQ_T + rowB) * CDIM + col] = f2bf(oB[nc][i] * iB[i]);
        }
}

// GEMM2: out(fp32) = att @ w_proj + b_proj. 1D grid 384, XCD-sliced like gemm_qkv.
__global__ __launch_bounds__(256) void gemm_proj(
    const unsigned short* __restrict__ attb, const unsigned short* __restrict__ wpT,
    const float* __restrict__ b_proj, float* __restrict__ out)
{
    __shared__ __align__(16) unsigned short As[128 * 64];
    __shared__ __align__(16) unsigned short Bs[128 * 64];
    f32x4_t acc[4][4];
    const int lid = blockIdx.x;
    const int xcd = lid & 7;
    const int j = lid >> 3;                 // 0..47
    const int mTile = xcd * 8 + (j & 7);    // 0..63
    const int nTile = j >> 3;               // 0..5
    const int mBase = mTile * 128;
    const int nBase = nTile * 128;
    gemm128_core(attb, wpT, As, Bs, acc, mBase, nBase);

    const int tid = threadIdx.x;
    const int lane = tid & 63, wv = tid >> 6;
    const int quad = lane >> 4, l16 = lane & 15;
    const int wm = (wv >> 1) * 64, wn = (wv & 1) * 64;

#pragma unroll
    for (int tn = 0; tn < 4; tn++) {
        int n = nBase + wn + tn * 16 + l16;
        float bv = b_proj[n];
#pragma unroll
        for (int tm = 0; tm < 4; tm++)
#pragma unroll
            for (int i = 0; i < 4; i++) {
                int row = mBase + wm + tm * 16 + quad * 4 + i;
                out[(size_t)row * CDIM + n] = acc[tm][tn][i] + bv;
            }
    }
}

extern "C" void kernel_launch(void* const* d_in, const int* in_sizes, int n_in,
                              void* d_out, int out_size, void* d_ws, size_t ws_size,
                              hipStream_t stream) {
    const float* x      = (const float*)d_in[0];  // [8,1024,768] fp32
    const float* w_attn = (const float*)d_in[1];  // [768,2304]   fp32
    const float* b_attn = (const float*)d_in[2];  // [2304]       fp32
    const float* w_proj = (const float*)d_in[3];  // [768,768]    fp32
    const float* b_proj = (const float*)d_in[4];  // [768]        fp32
    float* out = (float*)d_out;                   // [8,1024,768] fp32

    unsigned short* ws   = (unsigned short*)d_ws;
    unsigned short* waT  = ws;                    // [2304][768] bf16
    unsigned short* wpT  = waT + 1769472;         // [768][768]  bf16
    unsigned short* xbf  = wpT + 589824;          // [8192][768] bf16
    unsigned short* qbuf = xbf + 6291456;         // [B,H,T,D] (log2e-scaled)
    unsigned short* kbuf = qbuf + 6291456;        // [B,H,T,D]
    unsigned short* vbuf = kbuf + 6291456;        // [B,H,D,T]
    unsigned short* attb = vbuf + 6291456;        // [B,T,C]
    // ws use: 67,633,152 bytes

    cvt_x<<<dim3(6144), 256, 0, stream>>>((const float4*)x, (ushort4*)xbf, 1572864);
    cvt_transpose<<<dim3(72, 24), dim3(32, 8), 0, stream>>>(w_attn, waT, 768, 2304);
    cvt_transpose<<<dim3(24, 24), dim3(32, 8), 0, stream>>>(w_proj, wpT, 768, 768);
    gemm_qkv<<<dim3(1152), 256, 0, stream>>>(xbf, waT, b_attn, qbuf, kbuf, vbuf);
    attn_fused<<<dim3(96, 8), 256, 0, stream>>>(qbuf, kbuf, vbuf, attb);
    gemm_proj<<<dim3(384), 256, 0, stream>>>(attb, wpT, b_proj, out);
}